// Round 1
// 378.910 us; speedup vs baseline: 1.1450x; 1.1450x over previous
//
#include <hip/hip_runtime.h>

// GraphSAGE 3-layer, N=50000, E=1.6M, D=128.
// R6: bucketed CSR build — replaces 1.6M fine-grained global atomics
//     (hist_pos, 74us, 56MB write-through RMW) + scatter_edges + 3-phase scan
//     with a 2-level bucket sort: LDS histograms + 153K padded-sector atomics
//     + L2-local esrc scatter. GEMM/agg path unchanged from R5.

constexpr int N_NODES = 50000;
constexpr int N_EDGES = 1600000;
constexpr int D = 128;

constexpr int NBUCK = 392;                    // ceil(50176/128) node-range buckets
constexpr int BCAP  = 6144;                   // capacity per bucket (mean 4082, >30 sigma)
constexpr int EPB   = 4096;                   // edges per block in count/scatter
constexpr int CS_BLOCKS = (N_EDGES + EPB - 1) / EPB;   // 391
constexpr int GC_STRIDE = 16;                 // 64B pad: 1 atomic counter per sector

typedef __bf16 bf16x8 __attribute__((ext_vector_type(8)));
typedef float f32x4 __attribute__((ext_vector_type(4)));
union U8 { bf16x8 v; __bf16 e[8]; };

// ---------------- zero ----------------------------------------------------
__global__ void zero1(int* __restrict__ a, int n) {
    int i = blockIdx.x * blockDim.x + threadIdx.x;
    if (i < n) a[i] = 0;
}

// ---------------- bucket count + scatter ----------------------------------
// Per block: LDS hist over 392 buckets (dst>>7), reserve space per bucket with
// ONE padded global atomic, then write packed (dstlow<<16 | src) to bucketbuf.
__global__ __launch_bounds__(256) void bucket_count_scatter(
        const int* __restrict__ dst, const int* __restrict__ src,
        int* __restrict__ gcursor, int* __restrict__ bucketbuf) {
    __shared__ int hcnt[NBUCK];
    __shared__ int hbase[NBUCK];
    const int tid = threadIdx.x;
    for (int i = tid; i < NBUCK; i += 256) hcnt[i] = 0;
    __syncthreads();

    const int e0 = blockIdx.x * EPB;
    int d[16], lp[16];
    #pragma unroll
    for (int t = 0; t < 16; ++t) {
        const int e = e0 + t * 256 + tid;
        if (e < N_EDGES) {
            d[t] = dst[e];
            lp[t] = atomicAdd(&hcnt[d[t] >> 7], 1);   // LDS atomic, returns local pos
        } else {
            d[t] = 0; lp[t] = -1;
        }
    }
    __syncthreads();

    for (int i = tid; i < NBUCK; i += 256) {
        const int c = hcnt[i];
        hbase[i] = c ? atomicAdd(&gcursor[i * GC_STRIDE], c) : 0;  // 1 per (blk,bucket)
    }
    __syncthreads();

    #pragma unroll
    for (int t = 0; t < 16; ++t) {
        const int e = e0 + t * 256 + tid;
        if (e < N_EDGES) {
            const int s  = src[e];
            const int bk = d[t] >> 7;
            const int p  = hbase[bk] + lp[t];
            if (p < BCAP)
                bucketbuf[bk * BCAP + p] = ((d[t] & 127) << 16) | s;
        }
    }
}

// ---------------- scan bucket totals -> bases ------------------------------
__global__ void bucket_scan(const int* __restrict__ gcursor,
                            int* __restrict__ bucket_base,
                            int* __restrict__ row_ptr) {
    __shared__ int wsum[8], wpre[8];
    const int t = threadIdx.x;                // 512 threads, 8 waves
    const int lane = t & 63, w = t >> 6;
    int v = 0;
    if (t < NBUCK) { v = gcursor[t * GC_STRIDE]; if (v > BCAP) v = BCAP; }
    int x = v;
    #pragma unroll
    for (int off = 1; off < 64; off <<= 1) {
        int tt = __shfl_up(x, off, 64);
        if (lane >= off) x += tt;
    }
    if (lane == 63) wsum[w] = x;
    __syncthreads();
    if (t < 8) {
        int s = wsum[t], y = s;
        #pragma unroll
        for (int off = 1; off < 8; off <<= 1) {
            int tt = __shfl_up(y, off, 64);
            if (t >= off) y += tt;
        }
        wpre[t] = y - s;
    }
    __syncthreads();
    if (t < NBUCK) bucket_base[t] = wpre[w] + (x - v);
    if (t == 0) row_ptr[N_NODES] = N_EDGES;
}

// ---------------- per-bucket CSR finalize ---------------------------------
// One block per bucket: LDS hist of 128 node counters -> row_ptr + inv_deg,
// then LDS-cursor scatter of esrc into the bucket's contiguous region.
__global__ __launch_bounds__(256) void bucket_csr(
        const int* __restrict__ gcursor, const int* __restrict__ bucket_base,
        const int* __restrict__ bucketbuf, int* __restrict__ row_ptr,
        float* __restrict__ inv_deg, int* __restrict__ esrc) {
    __shared__ int h[128];
    __shared__ int cur[128];
    __shared__ int s0tot;
    const int bk = blockIdx.x, tid = threadIdx.x;
    int cnt = gcursor[bk * GC_STRIDE];
    if (cnt > BCAP) cnt = BCAP;
    const int base = bucket_base[bk];
    if (tid < 128) h[tid] = 0;
    __syncthreads();

    const int* bb = bucketbuf + (size_t)bk * BCAP;
    for (int i = tid; i < cnt; i += 256) atomicAdd(&h[bb[i] >> 16], 1);
    __syncthreads();

    // scan 128 counters (waves 0+1 carry data; all threads run the pattern)
    const int c = (tid < 128) ? h[tid] : 0;
    int x = c;
    const int lane = tid & 63;
    #pragma unroll
    for (int off = 1; off < 64; off <<= 1) {
        int tt = __shfl_up(x, off, 64);
        if (lane >= off) x += tt;
    }
    if (tid == 63) s0tot = x;
    __syncthreads();
    const int excl = x - c + ((tid >= 64 && tid < 128) ? s0tot : 0);
    if (tid < 128) {
        cur[tid] = excl;
        const int node = (bk << 7) + tid;
        if (node < N_NODES) {
            row_ptr[node] = base + excl;
            inv_deg[node] = 1.0f / fmaxf((float)c, 1.0f);
        }
    }
    __syncthreads();

    for (int i = tid; i < cnt; i += 256) {
        const int p = bb[i];
        esrc[base + atomicAdd(&cur[p >> 16], 1)] = p & 0xFFFF;
    }
}

// ---------------- pack W into MFMA B-fragment order, hi+lo ---------------
// B[k][j] = W[j][k]; lane holds B[k0+(lane>>4)*8+t][j0+(lane&15)], t=0..7.
// out[mat][plane][((jt*4+ks)*64+lane)*8+t], plane 0=hi, 1=lo (16384 apart).
__global__ void pack_w(const float* __restrict__ w0, const float* __restrict__ w1,
                       const float* __restrict__ w2, const float* __restrict__ w3,
                       const float* __restrict__ w4, const float* __restrict__ w5,
                       __bf16* __restrict__ outbase) {
    const float* ws[6] = {w0, w1, w2, w3, w4, w5};
    const float* W = ws[blockIdx.y];
    __bf16* o = outbase + (size_t)blockIdx.y * 32768;
    int idx = blockIdx.x * 256 + threadIdx.x;   // 0..16383
    int t = idx & 7;
    int lane = (idx >> 3) & 63;
    int ks = (idx >> 9) & 3;
    int jt = idx >> 11;
    int j = jt * 16 + (lane & 15);
    int k = ks * 32 + (lane >> 4) * 8 + t;
    float w = W[j * D + k];
    __bf16 hi = (__bf16)w;
    o[idx] = hi;
    o[16384 + idx] = (__bf16)(w - (float)hi);
}

// ---------------- dual GEMM: y = h@Ws^T + b (fp32), z = h@Wn^T (bf16) ----
// One wave per 16-node tile; split-bf16 (3 products) for both matmuls.
__global__ __launch_bounds__(256) void dual_gemm(
        const float* __restrict__ h, const __bf16* __restrict__ Bs,
        const __bf16* __restrict__ Bn, const float* __restrict__ bias,
        float* __restrict__ y_self, __bf16* __restrict__ z) {
    const int wave = threadIdx.x >> 6;
    const int lane = threadIdx.x & 63;
    const int tile = blockIdx.x * 4 + wave;
    if (tile >= N_NODES / 16) return;
    const int n0 = tile * 16;
    const int row = n0 + (lane & 15);
    const int koff = (lane >> 4) * 8;

    U8 ahi[4], alo[4];
    #pragma unroll
    for (int ks = 0; ks < 4; ++ks) {
        const float* p = h + (size_t)row * D + ks * 32 + koff;
        float f[8];
        *(f32x4*)&f[0] = *(const f32x4*)p;
        *(f32x4*)&f[4] = *(const f32x4*)(p + 4);
        #pragma unroll
        for (int t = 0; t < 8; ++t) {
            __bf16 hi = (__bf16)f[t];
            ahi[ks].e[t] = hi;
            alo[ks].e[t] = (__bf16)(f[t] - (float)hi);
        }
    }

    const int jcol = lane & 15;
    const int r0 = (lane >> 4) * 4;

    #pragma unroll 2
    for (int jt = 0; jt < 8; ++jt) {
        f32x4 accS = {0.f, 0.f, 0.f, 0.f};
        f32x4 accN = {0.f, 0.f, 0.f, 0.f};
        #pragma unroll
        for (int ks = 0; ks < 4; ++ks) {
            const size_t off = (((size_t)jt * 4 + ks) * 64 + lane) * 8;
            bf16x8 wsh = *(const bf16x8*)(Bs + off);
            bf16x8 wsl = *(const bf16x8*)(Bs + 16384 + off);
            bf16x8 wnh = *(const bf16x8*)(Bn + off);
            bf16x8 wnl = *(const bf16x8*)(Bn + 16384 + off);
            accS = __builtin_amdgcn_mfma_f32_16x16x32_bf16(ahi[ks].v, wsh, accS, 0, 0, 0);
            accS = __builtin_amdgcn_mfma_f32_16x16x32_bf16(alo[ks].v, wsh, accS, 0, 0, 0);
            accS = __builtin_amdgcn_mfma_f32_16x16x32_bf16(ahi[ks].v, wsl, accS, 0, 0, 0);
            accN = __builtin_amdgcn_mfma_f32_16x16x32_bf16(ahi[ks].v, wnh, accN, 0, 0, 0);
            accN = __builtin_amdgcn_mfma_f32_16x16x32_bf16(alo[ks].v, wnh, accN, 0, 0, 0);
            accN = __builtin_amdgcn_mfma_f32_16x16x32_bf16(ahi[ks].v, wnl, accN, 0, 0, 0);
        }
        const int j = jt * 16 + jcol;
        const float bj = bias[j];
        #pragma unroll
        for (int r = 0; r < 4; ++r) {
            const size_t n = n0 + r0 + r;
            y_self[n * D + j] = accS[r] + bj;
            z[n * D + j] = (__bf16)accN[r];
        }
    }
}

// ---------------- aggregate z (bf16) + add y_self (+relu) ----------------
// One wave per node; 4 edge slots x 16 lanes x 16B chunks of the 256B row.
__global__ __launch_bounds__(256) void agg_add(
        const __bf16* __restrict__ z, const int* __restrict__ esrc,
        const int* __restrict__ row_ptr, const float* __restrict__ inv_deg,
        const float* __restrict__ y_self, float* __restrict__ out, int do_relu) {
    const int n = blockIdx.x * 4 + (threadIdx.x >> 6);
    const int lane = threadIdx.x & 63;
    const int s = lane >> 4;
    const int c = lane & 15;
    const int r0 = row_ptr[n], r1 = row_ptr[n + 1];

    float acc[8] = {0.f, 0.f, 0.f, 0.f, 0.f, 0.f, 0.f, 0.f};
    int e = r0 + s;
    for (; e + 12 < r1; e += 16) {
        int i0 = esrc[e], i1 = esrc[e + 4], i2 = esrc[e + 8], i3 = esrc[e + 12];
        U8 v0, v1, v2, v3;
        v0.v = *(const bf16x8*)(z + (size_t)i0 * D + c * 8);
        v1.v = *(const bf16x8*)(z + (size_t)i1 * D + c * 8);
        v2.v = *(const bf16x8*)(z + (size_t)i2 * D + c * 8);
        v3.v = *(const bf16x8*)(z + (size_t)i3 * D + c * 8);
        #pragma unroll
        for (int t = 0; t < 8; ++t)
            acc[t] += ((float)v0.e[t] + (float)v1.e[t]) + ((float)v2.e[t] + (float)v3.e[t]);
    }
    for (; e < r1; e += 4) {
        U8 v0;
        v0.v = *(const bf16x8*)(z + (size_t)esrc[e] * D + c * 8);
        #pragma unroll
        for (int t = 0; t < 8; ++t) acc[t] += (float)v0.e[t];
    }
    #pragma unroll
    for (int t = 0; t < 8; ++t) acc[t] += __shfl_down(acc[t], 32, 64);
    #pragma unroll
    for (int t = 0; t < 8; ++t) acc[t] += __shfl_down(acc[t], 16, 64);

    if (lane < 16) {
        const float idg = inv_deg[n];
        const float* yp = y_self + (size_t)n * D + c * 8;
        f32x4 y0 = *(const f32x4*)yp;
        f32x4 y1 = *(const f32x4*)(yp + 4);
        float o[8];
        #pragma unroll
        for (int t = 0; t < 4; ++t) o[t] = y0[t] + acc[t] * idg;
        #pragma unroll
        for (int t = 0; t < 4; ++t) o[4 + t] = y1[t] + acc[4 + t] * idg;
        if (do_relu) {
            #pragma unroll
            for (int t = 0; t < 8; ++t) o[t] = fmaxf(o[t], 0.f);
        }
        float* op = out + (size_t)n * D + c * 8;
        *(f32x4*)op = *(f32x4*)&o[0];
        *(f32x4*)(op + 4) = *(f32x4*)&o[4];
    }
}

extern "C" void kernel_launch(void* const* d_in, const int* in_sizes, int n_in,
                              void* d_out, int out_size, void* d_ws, size_t ws_size,
                              hipStream_t stream) {
    const float* x   = (const float*)d_in[0];
    const int* src   = (const int*)d_in[1];
    const int* dst   = (const int*)d_in[2];
    const float* Wn1 = (const float*)d_in[3];
    const float* Ws1 = (const float*)d_in[4];
    const float* b1  = (const float*)d_in[5];
    const float* Wn2 = (const float*)d_in[6];
    const float* Ws2 = (const float*)d_in[7];
    const float* b2  = (const float*)d_in[8];
    const float* Wn3 = (const float*)d_in[9];
    const float* Ws3 = (const float*)d_in[10];
    const float* b3  = (const float*)d_in[11];
    float* out = (float*)d_out;

    char* w = (char*)d_ws;
    float* inv_deg     = (float*)w;             w += 50176 * 4;
    int* row_ptr       = (int*)w;               w += 50432 * 4;
    int* gcursor       = (int*)w;               w += NBUCK * GC_STRIDE * 4;
    int* bucket_base   = (int*)w;               w += 512 * 4;
    int* esrc          = (int*)w;               w += (size_t)N_EDGES * 4;
    __bf16* Bpk        = (__bf16*)w;            w += 6 * 32768 * 2;
    __bf16* zbuf       = (__bf16*)w;            w += (size_t)50176 * D * 2;
    float* bufA        = (float*)w;             // N*D floats

    // bucketbuf (392*6144*4B = 9.63MB) aliases zbuf (12.8MB): consumed by
    // bucket_csr before dual_gemm first writes zbuf (stream-ordered).
    int* bucketbuf = (int*)zbuf;

    const __bf16* PWs1 = Bpk + 0 * 32768, *PWn1 = Bpk + 1 * 32768;
    const __bf16* PWs2 = Bpk + 2 * 32768, *PWn2 = Bpk + 3 * 32768;
    const __bf16* PWs3 = Bpk + 4 * 32768, *PWn3 = Bpk + 5 * 32768;

    // ---- CSR build (bucketed, no fine-grained global atomics) ----
    zero1<<<(NBUCK * GC_STRIDE + 255) / 256, 256, 0, stream>>>(gcursor, NBUCK * GC_STRIDE);
    bucket_count_scatter<<<CS_BLOCKS, 256, 0, stream>>>(dst, src, gcursor, bucketbuf);
    bucket_scan<<<1, 512, 0, stream>>>(gcursor, bucket_base, row_ptr);
    bucket_csr<<<NBUCK, 256, 0, stream>>>(gcursor, bucket_base, bucketbuf,
                                          row_ptr, inv_deg, esrc);

    // ---- pack weights (order: Ws1,Wn1,Ws2,Wn2,Ws3,Wn3) ----
    pack_w<<<dim3(64, 6), 256, 0, stream>>>(Ws1, Wn1, Ws2, Wn2, Ws3, Wn3, Bpk);

    const int ggrid = (N_NODES / 16 + 3) / 4;   // 782 blocks x 4 waves
    const int agrid = N_NODES / 4;              // 12500 blocks x 4 waves

    // layer 1: h=x -> bufA (relu)
    dual_gemm<<<ggrid, 256, 0, stream>>>(x, PWs1, PWn1, b1, bufA, zbuf);
    agg_add<<<agrid, 256, 0, stream>>>(zbuf, esrc, row_ptr, inv_deg, bufA, bufA, 1);

    // layer 2: h=bufA -> d_out (relu)
    dual_gemm<<<ggrid, 256, 0, stream>>>(bufA, PWs2, PWn2, b2, out, zbuf);
    agg_add<<<agrid, 256, 0, stream>>>(zbuf, esrc, row_ptr, inv_deg, out, out, 1);

    // layer 3: h=d_out -> d_out (no relu), y_self staged in bufA
    dual_gemm<<<ggrid, 256, 0, stream>>>(out, PWs3, PWn3, b3, bufA, zbuf);
    agg_add<<<agrid, 256, 0, stream>>>(zbuf, esrc, row_ptr, inv_deg, bufA, out, 0);
}